// Round 16
// baseline (235.750 us; speedup 1.0000x reference)
//
#include <hip/hip_runtime.h>

typedef float f32x4 __attribute__((ext_vector_type(4)));
typedef short bf16x8 __attribute__((ext_vector_type(8)));
typedef short bf16x4 __attribute__((ext_vector_type(4)));

#define PADN 1156  // 34*34

typedef const __attribute__((address_space(1))) void* gptr_t;
typedef __attribute__((address_space(3))) void* lptr_t;

__device__ __forceinline__ short f2b(float f) {
  unsigned u = __float_as_uint(f);
  unsigned r = (u + 0x7FFFu + ((u >> 16) & 1u)) >> 16;  // RNE
  return (short)r;
}
__device__ __forceinline__ float b2f(short s) {
  return __uint_as_float(((unsigned)(unsigned short)s) << 16);
}

// ---- fused prep: x transpose | W pack | Wout pack | borders | stats | pbuf zero ----------
// 0..2047 x-transpose | 2048..2815 W packs | 2880-era borders | 3012 stats | 3013..4548 pbuf
__global__ __launch_bounds__(256) void prep(const float* __restrict__ x,
                                            const float* __restrict__ Wq,
                                            const float* __restrict__ Wk,
                                            const float* __restrict__ Wv,
                                            const float* __restrict__ Wout,
                                            short* __restrict__ xpad,
                                            short* __restrict__ wpack,
                                            short* __restrict__ woutp,
                                            float* __restrict__ stats,
                                            float* __restrict__ pbuf) {
  __shared__ float lds[2304];
  int blk0 = blockIdx.x;
  int t = threadIdx.x;
  if (blk0 < 2048) {
    int wg = blk0;
    int b = wg >> 8, rem = wg & 255;
    int cb = rem >> 5, sb = rem & 31;
    int sl = t & 31, cq = t >> 5;
    const float* xb = x + ((b * 256 + cb * 32) * 1024) + sb * 32;
#pragma unroll
    for (int i = 0; i < 4; i++) {
      int cl = cq + i * 8;
      lds[cl * 33 + sl] = xb[cl * 1024 + sl];
    }
    __syncthreads();
    int cl2 = t & 31, sq = t >> 5;
    short* xp = xpad + b * (PADN * 256) + cb * 32 + cl2;
#pragma unroll
    for (int i = 0; i < 4; i++) {
      int sl2 = sq + i * 8;
      int s = sb * 32 + sl2;
      int pidx = ((s >> 5) + 1) * 34 + (s & 31) + 1;
      xp[pidx * 256] = f2b(lds[cl2 * 33 + sl2]);
    }
  } else if (blk0 < 2880) {
    int blk = blk0 - 2048;  // 0..831
    if (blk < 768) {
      int p = blk >> 8, o = blk & 255;
      const float* W = (p == 0) ? Wq : (p == 1) ? Wk : Wv;
      const float* src = W + o * 2304;
      for (int i = t; i < 2304; i += 256) lds[i] = src[i];
      __syncthreads();
      short* dst = wpack + p * 589824 + o * 2304;
#pragma unroll
      for (int tt = 0; tt < 9; tt++) dst[tt * 256 + t] = f2b(lds[t * 9 + tt]);
    } else {
      int e = (blk - 768) * 1024 + t * 4;
      f32x4 v = *(const f32x4*)(Wout + e);
      bf16x4 o4;
#pragma unroll
      for (int j = 0; j < 4; j++) o4[j] = f2b(v[j]);
      *(bf16x4*)(woutp + e) = o4;
    }
  } else if (blk0 < 3012) {
    int id = (blk0 - 2880) * 256 + t;  // < 33792
    int chunk = id & 31;
    int r2 = id >> 5;
    int pos = r2 % 132;
    int b = r2 / 132;
    int pidx;
    if (pos < 34) pidx = pos;
    else if (pos < 68) pidx = 1122 + (pos - 34);
    else if (pos < 100) pidx = (pos - 67) * 34;
    else pidx = (pos - 99) * 34 + 33;
    bf16x8 z = {};
    *(bf16x8*)(xpad + (size_t)b * (PADN * 256) + pidx * 256 + chunk * 8) = z;
  } else if (blk0 == 3012) {
    if (t < 64) stats[t] = 0.f;
  } else {
    // zero pbuf: 1536 blocks x 4096 floats
    float* dst = pbuf + (size_t)(blk0 - 3013) * 4096 + t * 4;
    f32x4 z = {};
#pragma unroll
    for (int i = 0; i < 4; i++) *(f32x4*)(dst + i * 1024) = z;
  }
}

// ---- conv3x3 implicit GEMM, split-K=2: bid 0..383 = half0 (ks 0..17), 384..767 = half1 ---
// Epilogue: fp32 atomicAdd into pbuf (exactly 2 commutative adds/elem -> deterministic).
// bid 768..2815: fused bias_mat.
__global__ __launch_bounds__(256, 2) void conv_gemm(const short* __restrict__ xpad,
                                                    const short* __restrict__ wpack,
                                                    float* __restrict__ pbuf,
                                                    const float* __restrict__ btab,
                                                    short* __restrict__ biasP) {
  __shared__ short ldsA[2][8192];
  __shared__ short ldsB[2][8192];
  int bid = blockIdx.x;
  int tid = threadIdx.x;
  if (bid >= 768) {
    const float L2E = 1.4426950408889634f;
#pragma unroll
    for (int it = 0; it < 4; it++) {
      int id = (bid - 768) * 1024 + it * 256 + tid;
      int lane = id & 63;
      int rest = id >> 6;
      int jt = rest & 3; rest >>= 2;
      int kb = rest & 15; rest >>= 4;
      int qblk = rest & 63; rest >>= 6;
      int h = rest;  // 0..7
      int li = lane & 15, g = lane >> 4;
      int qrow = qblk * 16 + li;
      int yi = qrow >> 5, xi = qrow & 31;
      int ibase = (yi + 31) * 63 + (xi + 31);
      int j0 = kb * 64 + jt * 16 + g * 4;
      int yj = j0 >> 5, xj0 = j0 & 31;
      int idx0 = ibase - yj * 63 - xj0;
      bf16x4 v;
#pragma unroll
      for (int rr = 0; rr < 4; rr++) v[rr] = f2b(btab[(idx0 - rr) * 8 + h] * L2E);
      *(bf16x4*)(biasP + (size_t)id * 4) = v;
    }
    return;
  }
  int half = (bid >= 384) ? 1 : 0;
  int tile = bid - half * 384;
  int ks0 = half * 18, ks1 = ks0 + 18;
  int wg = (tile & 7) * 48 + (tile >> 3);  // XCD-affinity swizzle (384 % 8 == 0)
  int b = wg / 48;
  int rr0 = wg - b * 48;
  int p = (rr0 < 16) ? 0 : (rr0 < 32) ? 1 : 2;
  int t16 = rr0 & 15;
  bool xA = (p < 2);
  int mt_i = xA ? (t16 >> 1) : (t16 >> 3);
  int nt_i = xA ? (t16 & 1) : (t16 & 7);
  int m0 = mt_i * 128, n0 = nt_i * 128;
  int lane = tid & 63, wave = tid >> 6;
  int wr = wave >> 1, wc = wave & 1;
  int g = lane >> 4, li = lane & 15;

  const char* xb = (const char*)(xpad + b * (PADN * 256));
  const char* wp = (const char*)(wpack + p * (256 * 2304));
  const char* abase = xA ? xb : wp;
  const char* bbase = xA ? wp : xb;

  int srow = tid >> 3;
  int schunk = ((tid & 7) ^ (srow & 7)) * 16;
  int aoff[4], boff[4];
#pragma unroll
  for (int q = 0; q < 4; q++) {
    int row = m0 + q * 32 + srow;
    aoff[q] = (xA ? ((((row >> 5) + 1) * 34 + (row & 31) + 1) * 512) : (row * 4608)) + schunk;
  }
#pragma unroll
  for (int q = 0; q < 4; q++) {
    int row = n0 + q * 32 + srow;
    boff[q] = (xA ? (row * 4608) : ((((row >> 5) + 1) * 34 + (row & 31) + 1) * 512)) + schunk;
  }

  int aadr[4][2], badr[4][2];
#pragma unroll
  for (int mt = 0; mt < 4; mt++) {
    int row = wr * 64 + mt * 16 + li;
#pragma unroll
    for (int ksub = 0; ksub < 2; ksub++)
      aadr[mt][ksub] = row * 64 + (((ksub * 4 + g) ^ (row & 7)) * 8);
  }
#pragma unroll
  for (int nt = 0; nt < 4; nt++) {
    int row = wc * 64 + nt * 16 + li;
#pragma unroll
    for (int ksub = 0; ksub < 2; ksub++)
      badr[nt][ksub] = row * 64 + (((ksub * 4 + g) ^ (row & 7)) * 8);
  }

#define STAGE(KS, BUF) do {                                                        \
    int t_ = (KS) >> 2, cq_ = (KS) & 3;                                            \
    int ty_ = (t_ * 11) >> 5;                                                      \
    int doff_ = (ty_ - 1) * 34 + (t_ - 3 * ty_) - 1;                               \
    int kA_ = (xA ? doff_ * 512 : t_ * 512) + cq_ * 128;                           \
    int kB_ = (xA ? t_ * 512 : doff_ * 512) + cq_ * 128;                           \
    _Pragma("unroll")                                                              \
    for (int q_ = 0; q_ < 4; q_++)                                                 \
      __builtin_amdgcn_global_load_lds((gptr_t)(abase + aoff[q_] + kA_),           \
                                       (lptr_t)&ldsA[BUF][(q_ * 256 + tid) * 8],   \
                                       16, 0, 0);                                  \
    _Pragma("unroll")                                                              \
    for (int q_ = 0; q_ < 4; q_++)                                                 \
      __builtin_amdgcn_global_load_lds((gptr_t)(bbase + boff[q_] + kB_),           \
                                       (lptr_t)&ldsB[BUF][(q_ * 256 + tid) * 8],   \
                                       16, 0, 0);                                  \
  } while (0)

  f32x4 acc[4][4] = {};
  STAGE(ks0, 0);
  __syncthreads();
#pragma unroll 2
  for (int ks = ks0; ks < ks1; ks++) {
    int cur = (ks - ks0) & 1;
    if (ks < ks1 - 1) STAGE(ks + 1, cur ^ 1);
    bf16x8 af[4][2], bfv[4][2];
#pragma unroll
    for (int mt = 0; mt < 4; mt++)
#pragma unroll
      for (int ksub = 0; ksub < 2; ksub++)
        af[mt][ksub] = *(const bf16x8*)&ldsA[cur][aadr[mt][ksub]];
#pragma unroll
    for (int nt = 0; nt < 4; nt++)
#pragma unroll
      for (int ksub = 0; ksub < 2; ksub++)
        bfv[nt][ksub] = *(const bf16x8*)&ldsB[cur][badr[nt][ksub]];
#pragma unroll
    for (int ksub = 0; ksub < 2; ksub++)
#pragma unroll
      for (int mt = 0; mt < 4; mt++)
#pragma unroll
        for (int nt = 0; nt < 4; nt++)
          acc[mt][nt] = __builtin_amdgcn_mfma_f32_16x16x32_bf16(af[mt][ksub], bfv[nt][ksub], acc[mt][nt], 0, 0, 0);
    __syncthreads();
  }
#undef STAGE

  // fp32 atomic accumulation; pbuf order [p][b][row*ostride+col]
  float* outp = pbuf + (size_t)p * 2097152 + (size_t)b * 262144;
  int ostride = xA ? 256 : 1024;
#pragma unroll
  for (int mt = 0; mt < 4; mt++)
#pragma unroll
    for (int nt = 0; nt < 4; nt++) {
      int col = n0 + wc * 64 + nt * 16 + li;
#pragma unroll
      for (int rr = 0; rr < 4; rr++) {
        int row = m0 + wr * 64 + mt * 16 + g * 4 + rr;
        atomicAdd(&outp[row * ostride + col], acc[mt][nt][rr]);
      }
    }
}

// ---- stats reduction: pbuf [p][b][262144] -> stats[(b*3+p)*2] = {sum, sumsq} --------------
__global__ __launch_bounds__(256) void statsred(const float* __restrict__ pbuf,
                                                float* __restrict__ stats) {
  int blk = blockIdx.x;  // 1536 = 3p * 8b * 64
  int tid = threadIdx.x;
  int p = blk >> 9;              // 512 blocks per p
  int b = (blk & 511) >> 6;      // 64 blocks per b
  const float* src = pbuf + (size_t)blk * 4096;
  float s1 = 0.f, s2 = 0.f;
#pragma unroll
  for (int i = 0; i < 4; i++) {
    f32x4 v = *(const f32x4*)(src + i * 1024 + tid * 4);
#pragma unroll
    for (int j = 0; j < 4; j++) {
      s1 += v[j];
      s2 += v[j] * v[j];
    }
  }
#pragma unroll
  for (int off = 1; off < 64; off <<= 1) {
    s1 += __shfl_xor(s1, off);
    s2 += __shfl_xor(s2, off);
  }
  if ((tid & 63) == 0) {
    atomicAdd(&stats[(b * 3 + p) * 2], s1);
    atomicAdd(&stats[(b * 3 + p) * 2 + 1], s2);
  }
}

// ---------------- GroupNorm(1) + exact GELU (fp32 in) -> fragment-packed outputs ----------
__global__ __launch_bounds__(256) void norm_gelu(const float* __restrict__ pbuf,
                                                 short* __restrict__ qpk, short* __restrict__ kpk,
                                                 short* __restrict__ vpk,
                                                 const float* __restrict__ stats,
                                                 const float* __restrict__ gq, const float* __restrict__ bq,
                                                 const float* __restrict__ gk, const float* __restrict__ bk,
                                                 const float* __restrict__ gv, const float* __restrict__ bv) {
  long e = ((long)blockIdx.x * 256 + threadIdx.x) * 8;
  int buf = (int)(e >> 21);
  int w = (int)(e & 2097151);
  int b = w >> 18;
  int pos = w & 262143;
  const float* base = pbuf + (size_t)buf * 2097152 + (size_t)b * 262144 + pos;
  const float* gg = (buf == 0) ? gq : (buf == 1) ? gk : gv;
  const float* bb = (buf == 0) ? bq : (buf == 1) ? bk : bv;
  float s1 = stats[(b * 3 + buf) * 2];
  float s2 = stats[(b * 3 + buf) * 2 + 1];
  float mean = s1 * (1.f / 262144.f);
  float var = s2 * (1.f / 262144.f) - mean * mean;
  float rstd = rsqrtf(var + 1e-6f);
  const float PS = 0.17677669529663687f * 1.4426950408889634f;  // scale * log2e
  float post = (buf == 0) ? PS : 1.f;
  f32x4 v0 = *(const f32x4*)(base);
  f32x4 v1 = *(const f32x4*)(base + 4);
  bf16x8 v;
#pragma unroll
  for (int j = 0; j < 8; j++) {
    int ch = (buf < 2) ? ((pos + j) & 255) : ((pos + j) >> 10);
    float y = (j < 4) ? v0[j] : v1[j - 4];
    y = (y - mean) * rstd * gg[ch] + bb[ch];
    y = 0.5f * y * (1.f + erff(y * 0.70710678118f));
    v[j] = f2b(y * post);
  }
  if (buf < 2) {
    int s = pos >> 8, c = pos & 255;
    int h2 = c >> 5, g2 = (c >> 3) & 3;
    short* dst = (buf == 0) ? qpk : kpk;
    size_t addr = ((size_t)((b * 8 + h2) * 64 + (s >> 4))) * 512 + (g2 * 16 + (s & 15)) * 8;
    *(bf16x8*)(dst + addr) = v;
  } else {
    int c = pos >> 10, s0 = pos & 1023;
    int h2 = c >> 5, d = c & 31;
    int dblk = d >> 4, liv = d & 15;
    int kv32 = s0 >> 5, jr0 = s0 & 31;
    int hi = jr0 >> 4, g0 = (jr0 >> 2) & 3;
    size_t addr = ((size_t)((b * 8 + h2) * 32 + kv32) * 2 + dblk) * 512 + hi * 4 + liv * 8;
    bf16x4 lo4 = {v[0], v[1], v[2], v[3]};
    bf16x4 hi4 = {v[4], v[5], v[6], v[7]};
    *(bf16x4*)(vpk + addr + g0 * 128) = lo4;
    *(bf16x4*)(vpk + addr + (g0 + 1) * 128) = hi4;
  }
}

// ---------------- flash attention: LDS-staged KV shared by 4 waves, setprio on MFMA -------
__global__ __launch_bounds__(256, 4) void attn(const short* __restrict__ qpk,
                                               const short* __restrict__ kpk,
                                               const short* __restrict__ vpk,
                                               const short* __restrict__ biasP,
                                               short* __restrict__ obuf) {
  __shared__ short ldsK[2][2048];
  __shared__ short ldsV[2][2048];
  int wg = blockIdx.x;
  int b = wg >> 7, rem = wg & 127;
  int h = rem >> 4, qt4 = rem & 15;
  int tid = threadIdx.x;
  int lane = tid & 63, wave = tid >> 6;
  int g = lane >> 4, li = lane & 15;
  int qblk = qt4 * 4 + wave;
  int qbase = qblk * 16;
  const short* qpb = qpk + ((size_t)((b * 8 + h) * 64 + qblk)) * 512;
  const char* kpc = (const char*)(kpk + ((size_t)((b * 8 + h) * 64)) * 512);
  const char* vpc = (const char*)(vpk + ((size_t)(b * 8 + h)) * 32768);
  const short* bpb = biasP + (((size_t)(h * 64 + qblk)) << 14) + lane * 4;
  bf16x8 qf = *(const bf16x8*)(qpb + lane * 8);
  float m = -1e30f, l = 0.f;
  f32x4 oacc[2] = {};
  bf16x4 bfr[4];
#pragma unroll
  for (int jt = 0; jt < 4; jt++) bfr[jt] = *(const bf16x4*)(bpb + jt * 256);
  __builtin_amdgcn_global_load_lds((gptr_t)(kpc + tid * 16), (lptr_t)&ldsK[0][tid * 8], 16, 0, 0);
  __builtin_amdgcn_global_load_lds((gptr_t)(vpc + tid * 16), (lptr_t)&ldsV[0][tid * 8], 16, 0, 0);
  __syncthreads();
#pragma unroll 1
  for (int kb = 0; kb < 16; kb++) {
    int cur = kb & 1;
    if (kb < 15) {
      __builtin_amdgcn_global_load_lds((gptr_t)(kpc + (kb + 1) * 4096 + tid * 16),
                                       (lptr_t)&ldsK[cur ^ 1][tid * 8], 16, 0, 0);
      __builtin_amdgcn_global_load_lds((gptr_t)(vpc + (kb + 1) * 4096 + tid * 16),
                                       (lptr_t)&ldsV[cur ^ 1][tid * 8], 16, 0, 0);
    }
    f32x4 st[4];
    __builtin_amdgcn_s_setprio(1);
#pragma unroll
    for (int jt = 0; jt < 4; jt++) {
      bf16x8 kf = *(const bf16x8*)&ldsK[cur][jt * 512 + lane * 8];
      f32x4 cinit;
#pragma unroll
      for (int rr = 0; rr < 4; rr++) cinit[rr] = b2f(bfr[jt][rr]);
      st[jt] = __builtin_amdgcn_mfma_f32_16x16x32_bf16(kf, qf, cinit, 0, 0, 0);
    }
    __builtin_amdgcn_s_setprio(0);
    bf16x4 bfr2[4];
    if (kb < 15) {
#pragma unroll
      for (int jt = 0; jt < 4; jt++)
        bfr2[jt] = *(const bf16x4*)(bpb + (kb + 1) * 1024 + jt * 256);
    }
    float mbl = -1e30f;
#pragma unroll
    for (int jt = 0; jt < 4; jt++)
#pragma unroll
      for (int rr = 0; rr < 4; rr++) mbl = fmaxf(mbl, st[jt][rr]);
    if (!__all(mbl <= m + 8.f)) {
      float mb = fmaxf(mbl, __shfl_xor(mbl, 16));
      mb = fmaxf(mb, __shfl_xor(mb, 32));
      float mnew = fmaxf(m, mb);
      float alpha = exp2f(m - mnew);
      m = mnew;
      l *= alpha;
#pragma unroll
      for (int rr = 0; rr < 4; rr++) {
        float ar = __shfl(alpha, (lane & 0x30) | (g * 4 + rr));
        oacc[0][rr] *= ar;
        oacc[1][rr] *= ar;
      }
    }
    float ls = 0.f;
    bf16x8 pf0, pf1;
#pragma unroll
    for (int jt = 0; jt < 4; jt++)
#pragma unroll
      for (int rr = 0; rr < 4; rr++) {
        float pe = exp2f(st[jt][rr] - m);
        ls += pe;
        int q2 = jt * 4 + rr;
        if (q2 < 8) pf0[q2] = f2b(pe); else pf1[q2 - 8] = f2b(pe);
      }
    l += ls;
    __builtin_amdgcn_s_setprio(1);
#pragma unroll
    for (int nt = 0; nt < 2; nt++)
#pragma unroll
      for (int ks = 0; ks < 2; ks++) {
        bf16x8 vf = *(const bf16x8*)&ldsV[cur][(ks * 2 + nt) * 512 + lane * 8];
        oacc[nt] = __builtin_amdgcn_mfma_f32_16x16x32_bf16(ks == 0 ? pf0 : pf1, vf, oacc[nt], 0, 0, 0);
      }
    __builtin_amdgcn_s_setprio(0);
    if (kb < 15) {
#pragma unroll
      for (int jt = 0; jt < 4; jt++) bfr[jt] = bfr2[jt];
    }
    __syncthreads();
  }
  l += __shfl_xor(l, 16);
  l += __shfl_xor(l, 32);
  float linv = 1.f / l;
  short* ob = obuf + (b * 1024) * 256 + h * 32;
#pragma unroll
  for (int rr = 0; rr < 4; rr++) {
    float lr = __shfl(linv, (lane & 0x30) | (g * 4 + rr));
    int row = qbase + g * 4 + rr;
    ob[row * 256 + li] = f2b(oacc[0][rr] * lr);
    ob[row * 256 + 16 + li] = f2b(oacc[1][rr] * lr);
  }
}

// ---------------- 1x1 conv out projection -> fp32 NCHW ------------------
__global__ __launch_bounds__(256) void out_gemm(const short* __restrict__ woutp,
                                                const short* __restrict__ obuf,
                                                const float* __restrict__ bout,
                                                float* __restrict__ out) {
  int wg = blockIdx.x;  // 256 = b*32 + mt*16 + nt
  int b = wg >> 5, rem = wg & 31;
  int mt_i = rem >> 4, nt_i = rem & 15;
  int m0 = mt_i * 128, n0 = nt_i * 64;
  int lane = threadIdx.x & 63, wave = threadIdx.x >> 6;
  int wr = wave >> 1, wc = wave & 1;
  int g = lane >> 4, li = lane & 15;
  int aoff[4];
#pragma unroll
  for (int mt = 0; mt < 4; mt++) aoff[mt] = (m0 + wr * 64 + mt * 16 + li) * 256;
  int boff[2];
#pragma unroll
  for (int nt = 0; nt < 2; nt++) boff[nt] = (b * 1024 + n0 + wc * 32 + nt * 16 + li) * 256;
  f32x4 acc[4][2] = {};
#pragma unroll
  for (int ks = 0; ks < 8; ks++) {
    int kof = ks * 32 + g * 8;
    bf16x8 af[4], bfr[2];
#pragma unroll
    for (int mt = 0; mt < 4; mt++) af[mt] = *(const bf16x8*)(woutp + aoff[mt] + kof);
#pragma unroll
    for (int nt = 0; nt < 2; nt++) bfr[nt] = *(const bf16x8*)(obuf + boff[nt] + kof);
#pragma unroll
    for (int mt = 0; mt < 4; mt++)
#pragma unroll
      for (int nt = 0; nt < 2; nt++)
        acc[mt][nt] = __builtin_amdgcn_mfma_f32_16x16x32_bf16(af[mt], bfr[nt], acc[mt][nt], 0, 0, 0);
  }
#pragma unroll
  for (int mt = 0; mt < 4; mt++)
#pragma unroll
    for (int nt = 0; nt < 2; nt++) {
      int col = n0 + wc * 32 + nt * 16 + li;
#pragma unroll
      for (int rr = 0; rr < 4; rr++) {
        int row = m0 + wr * 64 + mt * 16 + g * 4 + rr;
        out[b * 262144 + row * 1024 + col] = acc[mt][nt][rr] + bout[row];
      }
    }
}

extern "C" void kernel_launch(void* const* d_in, const int* in_sizes, int n_in,
                              void* d_out, int out_size, void* d_ws, size_t ws_size,
                              hipStream_t stream) {
  const float* x = (const float*)d_in[0];
  const float* Wq = (const float*)d_in[1];
  const float* gq = (const float*)d_in[2];
  const float* bq = (const float*)d_in[3];
  const float* Wk = (const float*)d_in[4];
  const float* gk = (const float*)d_in[5];
  const float* bk = (const float*)d_in[6];
  const float* Wv = (const float*)d_in[7];
  const float* gv = (const float*)d_in[8];
  const float* bv = (const float*)d_in[9];
  const float* btab = (const float*)d_in[10];
  const float* Wout = (const float*)d_in[11];
  const float* bout = (const float*)d_in[12];
  float* out = (float*)d_out;

  char* ws = (char*)d_ws;
  size_t off = 0;
  float* stats = (float*)(ws + off); off += 256;
  short* xpad = (short*)(ws + off); off += (size_t)8 * PADN * 256 * 2;   // 4,734,976
  short* wpack = (short*)(ws + off); off += (size_t)3 * 256 * 2304 * 2;  // 3,538,944
  short* woutp = (short*)(ws + off); off += (size_t)256 * 256 * 2;       // 131,072
  float* pbuf = (float*)(ws + off); off += (size_t)6291456 * 4;          // 25,165,824
  short* obuf = (short*)(ws + off); off += (size_t)4194304;
  short* qpk = (short*)(ws + off); off += (size_t)4194304;
  short* kpk = (short*)(ws + off); off += (size_t)4194304;
  short* vpk = (short*)(ws + off); off += (size_t)4194304;
  short* biasP = (short*)(ws + off); off += (size_t)8 * 1024 * 1024 * 2;  // 16,777,216
  if (ws_size < off) return;  // workspace too small -> loud failure

  prep<<<4549, 256, 0, stream>>>(x, Wq, Wk, Wv, Wout, xpad, wpack, woutp, stats, pbuf);
  conv_gemm<<<2816, 256, 0, stream>>>(xpad, wpack, pbuf, btab, biasP);
  statsred<<<1536, 256, 0, stream>>>(pbuf, stats);
  norm_gelu<<<3072, 256, 0, stream>>>(pbuf, qpk, kpk, vpk, stats, gq, bq, gk, bk, gv, bv);
  attn<<<1024, 256, 0, stream>>>(qpk, kpk, vpk, biasP, obuf);
  out_gemm<<<256, 256, 0, stream>>>(woutp, obuf, bout, out);
}

// Round 17
// 137.148 us; speedup vs baseline: 1.7189x; 1.7189x over previous
//
#include <hip/hip_runtime.h>

typedef float f32x4 __attribute__((ext_vector_type(4)));
typedef short bf16x8 __attribute__((ext_vector_type(8)));
typedef short bf16x4 __attribute__((ext_vector_type(4)));

#define PADN 1156  // 34*34

typedef const __attribute__((address_space(1))) void* gptr_t;
typedef __attribute__((address_space(3))) void* lptr_t;

__device__ __forceinline__ short f2b(float f) {
  unsigned u = __float_as_uint(f);
  unsigned r = (u + 0x7FFFu + ((u >> 16) & 1u)) >> 16;  // RNE
  return (short)r;
}
__device__ __forceinline__ float b2f(short s) {
  return __uint_as_float(((unsigned)(unsigned short)s) << 16);
}

// ---- fused prep: x transpose | W pack | Wout pack | xpad border-zero | stats zero --------
__global__ __launch_bounds__(256) void prep(const float* __restrict__ x,
                                            const float* __restrict__ Wq,
                                            const float* __restrict__ Wk,
                                            const float* __restrict__ Wv,
                                            const float* __restrict__ Wout,
                                            short* __restrict__ xpad,
                                            short* __restrict__ wpack,
                                            short* __restrict__ woutp,
                                            float* __restrict__ stats) {
  __shared__ float lds[2304];
  int blk0 = blockIdx.x;
  int t = threadIdx.x;
  if (blk0 < 2048) {
    int wg = blk0;
    int b = wg >> 8, rem = wg & 255;
    int cb = rem >> 5, sb = rem & 31;
    int sl = t & 31, cq = t >> 5;
    const float* xb = x + ((b * 256 + cb * 32) * 1024) + sb * 32;
#pragma unroll
    for (int i = 0; i < 4; i++) {
      int cl = cq + i * 8;
      lds[cl * 33 + sl] = xb[cl * 1024 + sl];
    }
    __syncthreads();
    int cl2 = t & 31, sq = t >> 5;
    short* xp = xpad + b * (PADN * 256) + cb * 32 + cl2;
#pragma unroll
    for (int i = 0; i < 4; i++) {
      int sl2 = sq + i * 8;
      int s = sb * 32 + sl2;
      int pidx = ((s >> 5) + 1) * 34 + (s & 31) + 1;
      xp[pidx * 256] = f2b(lds[cl2 * 33 + sl2]);
    }
  } else if (blk0 < 2880) {
    int blk = blk0 - 2048;  // 0..831
    if (blk < 768) {
      int p = blk >> 8, o = blk & 255;
      const float* W = (p == 0) ? Wq : (p == 1) ? Wk : Wv;
      const float* src = W + o * 2304;
      for (int i = t; i < 2304; i += 256) lds[i] = src[i];
      __syncthreads();
      short* dst = wpack + p * 589824 + o * 2304;
#pragma unroll
      for (int tt = 0; tt < 9; tt++) dst[tt * 256 + t] = f2b(lds[t * 9 + tt]);
    } else {
      int e = (blk - 768) * 1024 + t * 4;
      f32x4 v = *(const f32x4*)(Wout + e);
      bf16x4 o4;
#pragma unroll
      for (int j = 0; j < 4; j++) o4[j] = f2b(v[j]);
      *(bf16x4*)(woutp + e) = o4;
    }
  } else if (blk0 < 3012) {
    // zero xpad borders: 8 batches x 132 border cells x 256 ch (32 chunks of 8)
    int id = (blk0 - 2880) * 256 + t;  // < 33792
    int chunk = id & 31;
    int r2 = id >> 5;
    int pos = r2 % 132;
    int b = r2 / 132;
    int pidx;
    if (pos < 34) pidx = pos;                       // row 0
    else if (pos < 68) pidx = 1122 + (pos - 34);    // row 33
    else if (pos < 100) pidx = (pos - 67) * 34;     // col 0, rows 1..32
    else pidx = (pos - 99) * 34 + 33;               // col 33, rows 1..32
    bf16x8 z = {};
    *(bf16x8*)(xpad + (size_t)b * (PADN * 256) + pidx * 256 + chunk * 8) = z;
  } else {
    if (t < 64) stats[t] = 0.f;
  }
}

// ---------------- conv3x3 implicit GEMM (blocks 0..383, XCD-swizzled) + fused bias_mat ----
__global__ __launch_bounds__(256, 2) void conv_gemm(const short* __restrict__ xpad,
                                                    const short* __restrict__ wpack,
                                                    short* __restrict__ qn,
                                                    short* __restrict__ kn,
                                                    short* __restrict__ vn,
                                                    float* __restrict__ stats,
                                                    const float* __restrict__ btab,
                                                    short* __restrict__ biasP) {
  __shared__ short ldsA[2][8192];
  __shared__ short ldsB[2][8192];
  int bid = blockIdx.x;
  int tid = threadIdx.x;
  if (bid >= 384) {
    const float L2E = 1.4426950408889634f;
#pragma unroll
    for (int it = 0; it < 4; it++) {
      int id = (bid - 384) * 1024 + it * 256 + tid;
      int lane = id & 63;
      int rest = id >> 6;
      int jt = rest & 3; rest >>= 2;
      int kb = rest & 15; rest >>= 4;
      int qblk = rest & 63; rest >>= 6;
      int h = rest;  // 0..7
      int li = lane & 15, g = lane >> 4;
      int qrow = qblk * 16 + li;
      int yi = qrow >> 5, xi = qrow & 31;
      int ibase = (yi + 31) * 63 + (xi + 31);
      int j0 = kb * 64 + jt * 16 + g * 4;
      int yj = j0 >> 5, xj0 = j0 & 31;
      int idx0 = ibase - yj * 63 - xj0;
      bf16x4 v;
#pragma unroll
      for (int rr = 0; rr < 4; rr++) v[rr] = f2b(btab[(idx0 - rr) * 8 + h] * L2E);
      *(bf16x4*)(biasP + (size_t)id * 4) = v;
    }
    return;
  }
  // de-phase the second co-resident block on each CU (~2000 cy ≈ one K-step)
  if (bid >= 256) {
    __builtin_amdgcn_s_sleep(15);
    __builtin_amdgcn_s_sleep(15);
  }
  int wg = (bid & 7) * 48 + (bid >> 3);
  int b = wg / 48;
  int rr0 = wg - b * 48;
  int p = (rr0 < 16) ? 0 : (rr0 < 32) ? 1 : 2;
  int t16 = rr0 & 15;
  bool xA = (p < 2);
  int mt_i = xA ? (t16 >> 1) : (t16 >> 3);
  int nt_i = xA ? (t16 & 1) : (t16 & 7);
  int m0 = mt_i * 128, n0 = nt_i * 128;
  int lane = tid & 63, wave = tid >> 6;
  int wr = wave >> 1, wc = wave & 1;
  int g = lane >> 4, li = lane & 15;

  const char* xb = (const char*)(xpad + b * (PADN * 256));
  const char* wp = (const char*)(wpack + p * (256 * 2304));
  const char* abase = xA ? xb : wp;
  const char* bbase = xA ? wp : xb;

  int srow = tid >> 3;
  int schunk = ((tid & 7) ^ (srow & 7)) * 16;
  int aoff[4], boff[4];
#pragma unroll
  for (int q = 0; q < 4; q++) {
    int row = m0 + q * 32 + srow;
    aoff[q] = (xA ? ((((row >> 5) + 1) * 34 + (row & 31) + 1) * 512) : (row * 4608)) + schunk;
  }
#pragma unroll
  for (int q = 0; q < 4; q++) {
    int row = n0 + q * 32 + srow;
    boff[q] = (xA ? (row * 4608) : ((((row >> 5) + 1) * 34 + (row & 31) + 1) * 512)) + schunk;
  }

  int aadr[4][2], badr[4][2];
#pragma unroll
  for (int mt = 0; mt < 4; mt++) {
    int row = wr * 64 + mt * 16 + li;
#pragma unroll
    for (int ksub = 0; ksub < 2; ksub++)
      aadr[mt][ksub] = row * 64 + (((ksub * 4 + g) ^ (row & 7)) * 8);
  }
#pragma unroll
  for (int nt = 0; nt < 4; nt++) {
    int row = wc * 64 + nt * 16 + li;
#pragma unroll
    for (int ksub = 0; ksub < 2; ksub++)
      badr[nt][ksub] = row * 64 + (((ksub * 4 + g) ^ (row & 7)) * 8);
  }

#define STAGE(KS, BUF) do {                                                        \
    int t_ = (KS) >> 2, cq_ = (KS) & 3;                                            \
    int ty_ = (t_ * 11) >> 5;                                                      \
    int doff_ = (ty_ - 1) * 34 + (t_ - 3 * ty_) - 1;                               \
    int kA_ = (xA ? doff_ * 512 : t_ * 512) + cq_ * 128;                           \
    int kB_ = (xA ? t_ * 512 : doff_ * 512) + cq_ * 128;                           \
    _Pragma("unroll")                                                              \
    for (int q_ = 0; q_ < 4; q_++)                                                 \
      __builtin_amdgcn_global_load_lds((gptr_t)(abase + aoff[q_] + kA_),           \
                                       (lptr_t)&ldsA[BUF][(q_ * 256 + tid) * 8],   \
                                       16, 0, 0);                                  \
    _Pragma("unroll")                                                              \
    for (int q_ = 0; q_ < 4; q_++)                                                 \
      __builtin_amdgcn_global_load_lds((gptr_t)(bbase + boff[q_] + kB_),           \
                                       (lptr_t)&ldsB[BUF][(q_ * 256 + tid) * 8],   \
                                       16, 0, 0);                                  \
  } while (0)

  f32x4 acc[4][4] = {};
  STAGE(0, 0);
  __syncthreads();
#pragma unroll 2
  for (int ks = 0; ks < 36; ks++) {
    int cur = ks & 1;
    if (ks < 35) STAGE(ks + 1, cur ^ 1);
    bf16x8 af[4][2], bfv[4][2];
#pragma unroll
    for (int mt = 0; mt < 4; mt++)
#pragma unroll
      for (int ksub = 0; ksub < 2; ksub++)
        af[mt][ksub] = *(const bf16x8*)&ldsA[cur][aadr[mt][ksub]];
#pragma unroll
    for (int nt = 0; nt < 4; nt++)
#pragma unroll
      for (int ksub = 0; ksub < 2; ksub++)
        bfv[nt][ksub] = *(const bf16x8*)&ldsB[cur][badr[nt][ksub]];
#pragma unroll
    for (int ksub = 0; ksub < 2; ksub++)
#pragma unroll
      for (int mt = 0; mt < 4; mt++)
#pragma unroll
        for (int nt = 0; nt < 4; nt++)
          acc[mt][nt] = __builtin_amdgcn_mfma_f32_16x16x32_bf16(af[mt][ksub], bfv[nt][ksub], acc[mt][nt], 0, 0, 0);
    __syncthreads();
  }
#undef STAGE

  short* outp = (p == 0) ? qn : (p == 1) ? kn : vn;
  int ostride = xA ? 256 : 1024;
  int obase = b * 262144;
  float s1 = 0.f, s2 = 0.f;
#pragma unroll
  for (int mt = 0; mt < 4; mt++)
#pragma unroll
    for (int nt = 0; nt < 4; nt++) {
      int col = n0 + wc * 64 + nt * 16 + li;
#pragma unroll
      for (int rr = 0; rr < 4; rr++) {
        int row = m0 + wr * 64 + mt * 16 + g * 4 + rr;
        float v = acc[mt][nt][rr];
        s1 += v;
        s2 += v * v;
        outp[obase + row * ostride + col] = f2b(v);
      }
    }
#pragma unroll
  for (int off = 1; off < 64; off <<= 1) {
    s1 += __shfl_xor(s1, off);
    s2 += __shfl_xor(s2, off);
  }
  if (lane == 0) {
    atomicAdd(&stats[(b * 3 + p) * 2], s1);
    atomicAdd(&stats[(b * 3 + p) * 2 + 1], s2);
  }
}

// ---------------- GroupNorm(1) + exact GELU -> fragment-packed outputs --------------------
__global__ __launch_bounds__(256) void norm_gelu(const short* __restrict__ qn, const short* __restrict__ kn,
                                                 const short* __restrict__ vn,
                                                 short* __restrict__ qpk, short* __restrict__ kpk,
                                                 short* __restrict__ vpk,
                                                 const float* __restrict__ stats,
                                                 const float* __restrict__ gq, const float* __restrict__ bq,
                                                 const float* __restrict__ gk, const float* __restrict__ bk,
                                                 const float* __restrict__ gv, const float* __restrict__ bv) {
  long e = ((long)blockIdx.x * 256 + threadIdx.x) * 8;
  int buf = (int)(e >> 21);
  int w = (int)(e & 2097151);
  int b = w >> 18;
  int pos = w & 262143;
  const short* base = (buf == 0) ? qn : (buf == 1) ? kn : vn;
  const float* gg = (buf == 0) ? gq : (buf == 1) ? gk : gv;
  const float* bb = (buf == 0) ? bq : (buf == 1) ? bk : bv;
  float s1 = stats[(b * 3 + buf) * 2];
  float s2 = stats[(b * 3 + buf) * 2 + 1];
  float mean = s1 * (1.f / 262144.f);
  float var = s2 * (1.f / 262144.f) - mean * mean;
  float rstd = rsqrtf(var + 1e-6f);
  const float PS = 0.17677669529663687f * 1.4426950408889634f;  // scale * log2e
  float post = (buf == 0) ? PS : 1.f;
  bf16x8 v = *(const bf16x8*)(base + (size_t)b * 262144 + pos);
#pragma unroll
  for (int j = 0; j < 8; j++) {
    int ch = (buf < 2) ? ((pos + j) & 255) : ((pos + j) >> 10);
    float y = b2f(v[j]);
    y = (y - mean) * rstd * gg[ch] + bb[ch];
    y = 0.5f * y * (1.f + erff(y * 0.70710678118f));
    v[j] = f2b(y * post);
  }
  if (buf < 2) {
    int s = pos >> 8, c = pos & 255;
    int h2 = c >> 5, g2 = (c >> 3) & 3;
    short* dst = (buf == 0) ? qpk : kpk;
    size_t addr = ((size_t)((b * 8 + h2) * 64 + (s >> 4))) * 512 + (g2 * 16 + (s & 15)) * 8;
    *(bf16x8*)(dst + addr) = v;
  } else {
    int c = pos >> 10, s0 = pos & 1023;
    int h2 = c >> 5, d = c & 31;
    int dblk = d >> 4, liv = d & 15;
    int kv32 = s0 >> 5, jr0 = s0 & 31;
    int hi = jr0 >> 4, g0 = (jr0 >> 2) & 3;
    size_t addr = ((size_t)((b * 8 + h2) * 32 + kv32) * 2 + dblk) * 512 + hi * 4 + liv * 8;
    bf16x4 lo4 = {v[0], v[1], v[2], v[3]};
    bf16x4 hi4 = {v[4], v[5], v[6], v[7]};
    *(bf16x4*)(vpk + addr + g0 * 128) = lo4;
    *(bf16x4*)(vpk + addr + (g0 + 1) * 128) = hi4;
  }
}

// ---------------- flash attention: LDS-staged KV shared by 4 waves, setprio on MFMA -------
__global__ __launch_bounds__(256, 4) void attn(const short* __restrict__ qpk,
                                               const short* __restrict__ kpk,
                                               const short* __restrict__ vpk,
                                               const short* __restrict__ biasP,
                                               short* __restrict__ obuf) {
  __shared__ short ldsK[2][2048];  // [buf][jt*512 + lane*8]
  __shared__ short ldsV[2][2048];  // [buf][(ks*2+nt)*512 + lane*8]
  int wg = blockIdx.x;
  int b = wg >> 7, rem = wg & 127;
  int h = rem >> 4, qt4 = rem & 15;
  int tid = threadIdx.x;
  int lane = tid & 63, wave = tid >> 6;
  int g = lane >> 4, li = lane & 15;
  int qblk = qt4 * 4 + wave;
  int qbase = qblk * 16;
  const short* qpb = qpk + ((size_t)((b * 8 + h) * 64 + qblk)) * 512;
  const char* kpc = (const char*)(kpk + ((size_t)((b * 8 + h) * 64)) * 512);
  const char* vpc = (const char*)(vpk + ((size_t)(b * 8 + h)) * 32768);
  const short* bpb = biasP + (((size_t)(h * 64 + qblk)) << 14) + lane * 4;
  bf16x8 qf = *(const bf16x8*)(qpb + lane * 8);
  float m = -1e30f, l = 0.f;  // l = per-lane partial sum, reduced once at the end
  f32x4 oacc[2] = {};
  bf16x4 bfr[4];
#pragma unroll
  for (int jt = 0; jt < 4; jt++) bfr[jt] = *(const bf16x4*)(bpb + jt * 256);
  // prologue: stage kb=0
  __builtin_amdgcn_global_load_lds((gptr_t)(kpc + tid * 16), (lptr_t)&ldsK[0][tid * 8], 16, 0, 0);
  __builtin_amdgcn_global_load_lds((gptr_t)(vpc + tid * 16), (lptr_t)&ldsV[0][tid * 8], 16, 0, 0);
  __syncthreads();
#pragma unroll 1
  for (int kb = 0; kb < 16; kb++) {
    int cur = kb & 1;
    if (kb < 15) {
      __builtin_amdgcn_global_load_lds((gptr_t)(kpc + (kb + 1) * 4096 + tid * 16),
                                       (lptr_t)&ldsK[cur ^ 1][tid * 8], 16, 0, 0);
      __builtin_amdgcn_global_load_lds((gptr_t)(vpc + (kb + 1) * 4096 + tid * 16),
                                       (lptr_t)&ldsV[cur ^ 1][tid * 8], 16, 0, 0);
    }
    // QK^T with bias folded into the accumulator (logits already in exp2 domain)
    f32x4 st[4];
    __builtin_amdgcn_s_setprio(1);
#pragma unroll
    for (int jt = 0; jt < 4; jt++) {
      bf16x8 kf = *(const bf16x8*)&ldsK[cur][jt * 512 + lane * 8];
      f32x4 cinit;
#pragma unroll
      for (int rr = 0; rr < 4; rr++) cinit[rr] = b2f(bfr[jt][rr]);
      st[jt] = __builtin_amdgcn_mfma_f32_16x16x32_bf16(kf, qf, cinit, 0, 0, 0);
    }
    __builtin_amdgcn_s_setprio(0);
    // prefetch next bias fragment (register double-buffer)
    bf16x4 bfr2[4];
    if (kb < 15) {
#pragma unroll
      for (int jt = 0; jt < 4; jt++)
        bfr2[jt] = *(const bf16x4*)(bpb + (kb + 1) * 1024 + jt * 256);
    }
    // LOCAL max only; wave-uniform gate decides if a rescale is needed (m q-row-uniform).
    float mbl = -1e30f;
#pragma unroll
    for (int jt = 0; jt < 4; jt++)
#pragma unroll
      for (int rr = 0; rr < 4; rr++) mbl = fmaxf(mbl, st[jt][rr]);
    if (!__all(mbl <= m + 8.f)) {
      float mb = fmaxf(mbl, __shfl_xor(mbl, 16));
      mb = fmaxf(mb, __shfl_xor(mb, 32));
      float mnew = fmaxf(m, mb);
      float alpha = exp2f(m - mnew);
      m = mnew;
      l *= alpha;
#pragma unroll
      for (int rr = 0; rr < 4; rr++) {
        float ar = __shfl(alpha, (lane & 0x30) | (g * 4 + rr));
        oacc[0][rr] *= ar;
        oacc[1][rr] *= ar;
      }
    }
    float ls = 0.f;
    bf16x8 pf0, pf1;
#pragma unroll
    for (int jt = 0; jt < 4; jt++)
#pragma unroll
      for (int rr = 0; rr < 4; rr++) {
        float pe = exp2f(st[jt][rr] - m);
        ls += pe;
        int q2 = jt * 4 + rr;
        if (q2 < 8) pf0[q2] = f2b(pe); else pf1[q2 - 8] = f2b(pe);
      }
    l += ls;  // partial; no per-iteration shuffle
    // PV from LDS
    __builtin_amdgcn_s_setprio(1);
#pragma unroll
    for (int nt = 0; nt < 2; nt++)
#pragma unroll
      for (int ks = 0; ks < 2; ks++) {
        bf16x8 vf = *(const bf16x8*)&ldsV[cur][(ks * 2 + nt) * 512 + lane * 8];
        oacc[nt] = __builtin_amdgcn_mfma_f32_16x16x32_bf16(ks == 0 ? pf0 : pf1, vf, oacc[nt], 0, 0, 0);
      }
    __builtin_amdgcn_s_setprio(0);
    if (kb < 15) {
#pragma unroll
      for (int jt = 0; jt < 4; jt++) bfr[jt] = bfr2[jt];
    }
    __syncthreads();
  }
  // one-time l reduction across the 4 lanes of each q-row
  l += __shfl_xor(l, 16);
  l += __shfl_xor(l, 32);
  float linv = 1.f / l;
  short* ob = obuf + (b * 1024) * 256 + h * 32;
#pragma unroll
  for (int rr = 0; rr < 4; rr++) {
    float lr = __shfl(linv, (lane & 0x30) | (g * 4 + rr));
    int row = qbase + g * 4 + rr;
    ob[row * 256 + li] = f2b(oacc[0][rr] * lr);
    ob[row * 256 + 16 + li] = f2b(oacc[1][rr] * lr);
  }
}

// ---------------- 1x1 conv out projection -> fp32 NCHW ------------------
__global__ __launch_bounds__(256) void out_gemm(const short* __restrict__ woutp,
                                                const short* __restrict__ obuf,
                                                const float* __restrict__ bout,
                                                float* __restrict__ out) {
  int wg = blockIdx.x;  // 256 = b*32 + mt*16 + nt
  int b = wg >> 5, rem = wg & 31;
  int mt_i = rem >> 4, nt_i = rem & 15;
  int m0 = mt_i * 128, n0 = nt_i * 64;
  int lane = threadIdx.x & 63, wave = threadIdx.x >> 6;
  int wr = wave >> 1, wc = wave & 1;
  int g = lane >> 4, li = lane & 15;
  int aoff[4];
#pragma unroll
  for (int mt = 0; mt < 4; mt++) aoff[mt] = (m0 + wr * 64 + mt * 16 + li) * 256;
  int boff[2];
#pragma unroll
  for (int nt = 0; nt < 2; nt++) boff[nt] = (b * 1024 + n0 + wc * 32 + nt * 16 + li) * 256;
  f32x4 acc[4][2] = {};
#pragma unroll
  for (int ks = 0; ks < 8; ks++) {
    int kof = ks * 32 + g * 8;
    bf16x8 af[4], bfr[2];
#pragma unroll
    for (int mt = 0; mt < 4; mt++) af[mt] = *(const bf16x8*)(woutp + aoff[mt] + kof);
#pragma unroll
    for (int nt = 0; nt < 2; nt++) bfr[nt] = *(const bf16x8*)(obuf + boff[nt] + kof);
#pragma unroll
    for (int mt = 0; mt < 4; mt++)
#pragma unroll
      for (int nt = 0; nt < 2; nt++)
        acc[mt][nt] = __builtin_amdgcn_mfma_f32_16x16x32_bf16(af[mt], bfr[nt], acc[mt][nt], 0, 0, 0);
  }
#pragma unroll
  for (int mt = 0; mt < 4; mt++)
#pragma unroll
    for (int nt = 0; nt < 2; nt++) {
      int col = n0 + wc * 32 + nt * 16 + li;
#pragma unroll
      for (int rr = 0; rr < 4; rr++) {
        int row = m0 + wr * 64 + mt * 16 + g * 4 + rr;
        out[b * 262144 + row * 1024 + col] = acc[mt][nt][rr] + bout[row];
      }
    }
}

extern "C" void kernel_launch(void* const* d_in, const int* in_sizes, int n_in,
                              void* d_out, int out_size, void* d_ws, size_t ws_size,
                              hipStream_t stream) {
  const float* x = (const float*)d_in[0];
  const float* Wq = (const float*)d_in[1];
  const float* gq = (const float*)d_in[2];
  const float* bq = (const float*)d_in[3];
  const float* Wk = (const float*)d_in[4];
  const float* gk = (const float*)d_in[5];
  const float* bk = (const float*)d_in[6];
  const float* Wv = (const float*)d_in[7];
  const float* gv = (const float*)d_in[8];
  const float* bv = (const float*)d_in[9];
  const float* btab = (const float*)d_in[10];
  const float* Wout = (const float*)d_in[11];
  const float* bout = (const float*)d_in[12];
  float* out = (float*)d_out;

  char* ws = (char*)d_ws;
  size_t off = 0;
  float* stats = (float*)(ws + off); off += 256;
  short* xpad = (short*)(ws + off); off += (size_t)8 * PADN * 256 * 2;   // 4,734,976
  short* wpack = (short*)(ws + off); off += (size_t)3 * 256 * 2304 * 2;  // 3,538,944
  short* woutp = (short*)(ws + off); off += (size_t)256 * 256 * 2;       // 131,072
  short* qn = (short*)(ws + off); off += (size_t)4194304;
  short* kn = (short*)(ws + off); off += (size_t)4194304;
  short* vn = (short*)(ws + off); off += (size_t)4194304;
  short* obuf = (short*)(ws + off); off += (size_t)4194304;
  short* qpk = (short*)(ws + off); off += (size_t)4194304;
  short* kpk = (short*)(ws + off); off += (size_t)4194304;
  short* vpk = (short*)(ws + off); off += (size_t)4194304;
  short* biasP = (short*)(ws + off); off += (size_t)8 * 1024 * 1024 * 2;  // 16,777,216
  if (ws_size < off) return;  // workspace too small -> loud failure

  prep<<<3013, 256, 0, stream>>>(x, Wq, Wk, Wv, Wout, xpad, wpack, woutp, stats);
  conv_gemm<<<2432, 256, 0, stream>>>(xpad, wpack, qn, kn, vn, stats, btab, biasP);
  norm_gelu<<<3072, 256, 0, stream>>>(qn, kn, vn, qpk, kpk, vpk, stats, gq, bq, gk, bk, gv, bv);
  attn<<<1024, 256, 0, stream>>>(qpk, kpk, vpk, biasP, obuf);
  out_gemm<<<256, 256, 0, stream>>>(woutp, obuf, bout, out);
}